// Round 1
// baseline (526.799 us; speedup 1.0000x reference)
//
#include <hip/hip_runtime.h>
#include <math.h>

#define NB 8
#define NN 10000
#define NE 160000
#define FD 64
#define BN (NB * NN)      // 80000
#define TOTE (NB * NE)    // 1280000

// ---------------- degree count ----------------
__global__ __launch_bounds__(256) void k_count(const int* __restrict__ ei,
                                               int* __restrict__ deg) {
    int e = blockIdx.x * 256 + threadIdx.x;
    if (e >= TOTE) return;
    int b = e / NE;
    int r = ei[2 * e] + b * NN;
    atomicAdd(&deg[r], 1);
}

// ---------------- dinv = deg^-0.5 ----------------
__global__ __launch_bounds__(256) void k_dinv(const int* __restrict__ deg,
                                              float* __restrict__ dinv) {
    int i = blockIdx.x * 256 + threadIdx.x;
    if (i >= BN) return;
    int d = deg[i];
    dinv[i] = (d > 0) ? (1.0f / sqrtf((float)d)) : 0.0f;
}

// ---------------- single-block exclusive scan over deg -> row_start ----------------
__global__ __launch_bounds__(1024) void k_scan(const int* __restrict__ deg,
                                               int* __restrict__ row_start) {
    __shared__ int wsums[16];
    __shared__ int carry_s;
    if (threadIdx.x == 0) carry_s = 0;
    __syncthreads();
    const int lane = threadIdx.x & 63;
    const int wv = threadIdx.x >> 6;
    for (int base = 0; base < BN; base += 1024) {
        int i = base + (int)threadIdx.x;
        int v = (i < BN) ? deg[i] : 0;
        int x = v;
#pragma unroll
        for (int off = 1; off < 64; off <<= 1) {
            int y = __shfl_up(x, off);
            if (lane >= off) x += y;
        }
        if (lane == 63) wsums[wv] = x;
        __syncthreads();
        if (wv == 0 && lane < 16) {
            int s = wsums[lane];
#pragma unroll
            for (int off = 1; off < 16; off <<= 1) {
                int y = __shfl_up(s, off, 16);
                if (lane >= off) s += y;
            }
            wsums[lane] = s;
        }
        __syncthreads();
        int excl = carry_s + ((wv > 0) ? wsums[wv - 1] : 0) + (x - v);
        if (i < BN) row_start[i] = excl;
        __syncthreads();
        if (threadIdx.x == 0) carry_s += wsums[15];
        __syncthreads();
    }
    if (threadIdx.x == 0) row_start[BN] = carry_s;
}

// ---------------- fill CSR (col + norm) ----------------
__global__ __launch_bounds__(256) void k_fill(const int* __restrict__ ei,
                                              const int* __restrict__ row_start,
                                              int* __restrict__ cursor,
                                              const float* __restrict__ dinv,
                                              int* __restrict__ col_arr,
                                              float* __restrict__ norm_arr) {
    int e = blockIdx.x * 256 + threadIdx.x;
    if (e >= TOTE) return;
    int b = e / NE;
    int r = ei[2 * e] + b * NN;
    int c = ei[2 * e + 1] + b * NN;
    int pos = row_start[r] + atomicAdd(&cursor[r], 1);
    col_arr[pos] = c;
    norm_arr[pos] = dinv[r] * dinv[c];
}

// ---------------- linear: t[n][j] = (act(h[n]) @ W^T + b)[j] ----------------
// thread-per-row; W transposed in LDS, broadcast float4 reads (conflict-free).
template <int RELU>
__global__ __launch_bounds__(256) void k_linear(const float* __restrict__ hin,
                                                const float* __restrict__ W,
                                                const float* __restrict__ bias,
                                                float* __restrict__ tout) {
    __shared__ __align__(16) float Wt[FD * FD];  // Wt[k*64 + j] = W[j*64 + k]
    __shared__ float bsh[FD];
    for (int idx = threadIdx.x; idx < FD * FD; idx += 256) {
        int j = idx >> 6, k = idx & 63;
        Wt[k * FD + j] = W[idx];
    }
    if (threadIdx.x < FD) bsh[threadIdx.x] = bias[threadIdx.x];
    __syncthreads();

    int n = blockIdx.x * 256 + threadIdx.x;
    if (n >= BN) return;

    float acc[FD];
#pragma unroll
    for (int j = 0; j < FD; j++) acc[j] = bsh[j];

    const float4* hp = (const float4*)(hin + (size_t)n * FD);
#pragma unroll
    for (int k4 = 0; k4 < 16; k4++) {
        float4 hv = hp[k4];
        if (RELU) {
            hv.x = fmaxf(hv.x, 0.f);
            hv.y = fmaxf(hv.y, 0.f);
            hv.z = fmaxf(hv.z, 0.f);
            hv.w = fmaxf(hv.w, 0.f);
        }
        float hk[4] = {hv.x, hv.y, hv.z, hv.w};
#pragma unroll
        for (int kk = 0; kk < 4; kk++) {
            const float4* wr = (const float4*)(&Wt[(k4 * 4 + kk) * FD]);
            float h = hk[kk];
#pragma unroll
            for (int j4 = 0; j4 < 16; j4++) {
                float4 w = wr[j4];
                acc[4 * j4 + 0] += h * w.x;
                acc[4 * j4 + 1] += h * w.y;
                acc[4 * j4 + 2] += h * w.z;
                acc[4 * j4 + 3] += h * w.w;
            }
        }
    }
    float4* op = (float4*)(tout + (size_t)n * FD);
#pragma unroll
    for (int j4 = 0; j4 < 16; j4++)
        op[j4] = make_float4(acc[4 * j4], acc[4 * j4 + 1], acc[4 * j4 + 2], acc[4 * j4 + 3]);
}

// ---------------- aggregate (pull, CSR): out[d][f] = sum_e norm[e]*t[col[e]][f] ----------------
__global__ __launch_bounds__(256) void k_agg(const float* __restrict__ t,
                                             const int* __restrict__ row_start,
                                             const int* __restrict__ col_arr,
                                             const float* __restrict__ norm_arr,
                                             float* __restrict__ out) {
    int node = (blockIdx.x * 256 + threadIdx.x) >> 6;
    int lane = threadIdx.x & 63;
    if (node >= BN) return;
    int p = row_start[node];
    int pe = row_start[node + 1];
    float acc = 0.f;
    // 4-edge unroll: keep 4 independent gathers in flight
    for (; p + 3 < pe; p += 4) {
        int c0 = col_arr[p + 0], c1 = col_arr[p + 1], c2 = col_arr[p + 2], c3 = col_arr[p + 3];
        float n0 = norm_arr[p + 0], n1 = norm_arr[p + 1], n2 = norm_arr[p + 2], n3 = norm_arr[p + 3];
        float t0 = t[(size_t)c0 * FD + lane];
        float t1 = t[(size_t)c1 * FD + lane];
        float t2 = t[(size_t)c2 * FD + lane];
        float t3 = t[(size_t)c3 * FD + lane];
        acc += n0 * t0 + n1 * t1 + n2 * t2 + n3 * t3;
    }
    for (; p < pe; p++) {
        int c = col_arr[p];
        float nm = norm_arr[p];
        acc += nm * t[(size_t)c * FD + lane];
    }
    out[(size_t)node * FD + lane] = acc;
}

extern "C" void kernel_launch(void* const* d_in, const int* in_sizes, int n_in,
                              void* d_out, int out_size, void* d_ws, size_t ws_size,
                              hipStream_t stream) {
    const float* x  = (const float*)d_in[0];
    const int*   ei = (const int*)d_in[1];
    const float* W1 = (const float*)d_in[2];
    const float* b1 = (const float*)d_in[3];
    const float* W2 = (const float*)d_in[4];
    const float* b2 = (const float*)d_in[5];
    const float* W3 = (const float*)d_in[6];
    const float* b3 = (const float*)d_in[7];
    float* out = (float*)d_out;

    char* ws = (char*)d_ws;
    size_t off = 0;
    float* t        = (float*)(ws + off); off += (size_t)BN * FD * 4;   // 20.48 MB
    int*   col_arr  = (int*)(ws + off);   off += (size_t)TOTE * 4;      // 5.12 MB
    float* norm_arr = (float*)(ws + off); off += (size_t)TOTE * 4;      // 5.12 MB
    int*   deg      = (int*)(ws + off);   off += (size_t)BN * 4;
    int*   cursor   = (int*)(ws + off);   off += (size_t)BN * 4;
    int*   row_start= (int*)(ws + off);   off += (size_t)(BN + 1) * 4;
    float* dinv     = (float*)(ws + off); off += (size_t)BN * 4;

    // deg and cursor are adjacent -> single memset clears both
    hipMemsetAsync(deg, 0, (size_t)BN * 4 * 2, stream);

    const int eb = (TOTE + 255) / 256;      // 5000
    const int nb = (BN + 255) / 256;        // 313
    const int ab = (BN * 64 + 255) / 256;   // 20000

    k_count<<<eb, 256, 0, stream>>>(ei, deg);
    k_dinv<<<nb, 256, 0, stream>>>(deg, dinv);
    k_scan<<<1, 1024, 0, stream>>>(deg, row_start);
    k_fill<<<eb, 256, 0, stream>>>(ei, row_start, cursor, dinv, col_arr, norm_arr);

    // layer 1: t = x@W1^T + b1 ; h1 = agg(t) -> out
    k_linear<0><<<nb, 256, 0, stream>>>(x, W1, b1, t);
    k_agg<<<ab, 256, 0, stream>>>(t, row_start, col_arr, norm_arr, out);
    // layer 2: t = relu(h1)@W2^T + b2 ; h2 = agg(t) -> out (overwrites h1)
    k_linear<1><<<nb, 256, 0, stream>>>(out, W2, b2, t);
    k_agg<<<ab, 256, 0, stream>>>(t, row_start, col_arr, norm_arr, out);
    // layer 3: t = relu(h2)@W3^T + b3 ; out = agg(t)
    k_linear<1><<<nb, 256, 0, stream>>>(out, W3, b3, t);
    k_agg<<<ab, 256, 0, stream>>>(t, row_start, col_arr, norm_arr, out);
}

// Round 2
// 378.429 us; speedup vs baseline: 1.3921x; 1.3921x over previous
//
#include <hip/hip_runtime.h>
#include <math.h>

#define NB 8
#define NN 10000
#define NE 160000
#define FD 64
#define BN (NB * NN)      // 80000
#define TOTE (NB * NE)    // 1280000
#define NBLK ((BN + 255) / 256)   // 313

// ---------------- degree count + per-edge rank ----------------
__global__ __launch_bounds__(256) void k_count(const int* __restrict__ ei,
                                               int* __restrict__ deg,
                                               int* __restrict__ rank) {
    int e = blockIdx.x * 256 + threadIdx.x;
    if (e >= TOTE) return;
    int b = e / NE;
    int r = ei[2 * e] + b * NN;
    rank[e] = atomicAdd(&deg[r], 1);
}

// ---------------- phase 1: dinv + per-block sum of deg ----------------
__global__ __launch_bounds__(256) void k_dinv_reduce(const int* __restrict__ deg,
                                                     float* __restrict__ dinv,
                                                     int* __restrict__ blocksum) {
    __shared__ int wsum[4];
    int i = blockIdx.x * 256 + threadIdx.x;
    int lane = threadIdx.x & 63;
    int wv = threadIdx.x >> 6;
    int d = (i < BN) ? deg[i] : 0;
    if (i < BN) dinv[i] = (d > 0) ? (1.0f / sqrtf((float)d)) : 0.0f;
    int s = d;
#pragma unroll
    for (int off = 32; off > 0; off >>= 1) s += __shfl_down(s, off);
    if (lane == 0) wsum[wv] = s;
    __syncthreads();
    if (threadIdx.x == 0)
        blocksum[blockIdx.x] = wsum[0] + wsum[1] + wsum[2] + wsum[3];
}

// ---------------- phase 2: 1-wave exclusive scan of 313 block sums ----------------
__global__ __launch_bounds__(64) void k_scanblk(const int* __restrict__ blocksum,
                                                int* __restrict__ blockoff,
                                                int* __restrict__ row_start) {
    int lane = threadIdx.x;
    int carry = 0;
    for (int base = 0; base < NBLK; base += 64) {
        int i = base + lane;
        int v = (i < NBLK) ? blocksum[i] : 0;
        int x = v;
#pragma unroll
        for (int off = 1; off < 64; off <<= 1) {
            int y = __shfl_up(x, off);
            if (lane >= off) x += y;
        }
        if (i < NBLK) blockoff[i] = carry + (x - v);
        carry += __shfl(x, 63);
    }
    if (lane == 0) row_start[BN] = carry;
}

// ---------------- phase 3: per-block rescan -> row_start ----------------
__global__ __launch_bounds__(256) void k_scan2(const int* __restrict__ deg,
                                               const int* __restrict__ blockoff,
                                               int* __restrict__ row_start) {
    __shared__ int wsum[4];
    int i = blockIdx.x * 256 + threadIdx.x;
    int lane = threadIdx.x & 63;
    int wv = threadIdx.x >> 6;
    int v = (i < BN) ? deg[i] : 0;
    int x = v;
#pragma unroll
    for (int off = 1; off < 64; off <<= 1) {
        int y = __shfl_up(x, off);
        if (lane >= off) x += y;
    }
    if (lane == 63) wsum[wv] = x;
    __syncthreads();
    int add = 0;
    for (int w = 0; w < wv; w++) add += wsum[w];
    if (i < BN) row_start[i] = blockoff[blockIdx.x] + add + (x - v);
}

// ---------------- fill CSR: edge_cn[pos] = {col, norm} (atomic-free) ----------------
__global__ __launch_bounds__(256) void k_fill(const int* __restrict__ ei,
                                              const int* __restrict__ row_start,
                                              const int* __restrict__ rank,
                                              const float* __restrict__ dinv,
                                              int2* __restrict__ edge_cn) {
    int e = blockIdx.x * 256 + threadIdx.x;
    if (e >= TOTE) return;
    int b = e / NE;
    int r = ei[2 * e] + b * NN;
    int c = ei[2 * e + 1] + b * NN;
    int pos = row_start[r] + rank[e];
    float nm = dinv[r] * dinv[c];
    edge_cn[pos] = make_int2(c, __float_as_int(nm));
}

// ---------------- linear: t[n][j] = (act(h[n]) @ W^T + b)[j] ----------------
template <int RELU>
__global__ __launch_bounds__(256) void k_linear(const float* __restrict__ hin,
                                                const float* __restrict__ W,
                                                const float* __restrict__ bias,
                                                float* __restrict__ tout) {
    __shared__ __align__(16) float Wt[FD * FD];  // Wt[k*64 + j] = W[j*64 + k]
    __shared__ float bsh[FD];
    for (int idx = threadIdx.x; idx < FD * FD; idx += 256) {
        int j = idx >> 6, k = idx & 63;
        Wt[k * FD + j] = W[idx];
    }
    if (threadIdx.x < FD) bsh[threadIdx.x] = bias[threadIdx.x];
    __syncthreads();

    int n = blockIdx.x * 256 + threadIdx.x;
    if (n >= BN) return;

    float acc[FD];
#pragma unroll
    for (int j = 0; j < FD; j++) acc[j] = bsh[j];

    const float4* hp = (const float4*)(hin + (size_t)n * FD);
#pragma unroll
    for (int k4 = 0; k4 < 16; k4++) {
        float4 hv = hp[k4];
        if (RELU) {
            hv.x = fmaxf(hv.x, 0.f);
            hv.y = fmaxf(hv.y, 0.f);
            hv.z = fmaxf(hv.z, 0.f);
            hv.w = fmaxf(hv.w, 0.f);
        }
        float hk[4] = {hv.x, hv.y, hv.z, hv.w};
#pragma unroll
        for (int kk = 0; kk < 4; kk++) {
            const float4* wr = (const float4*)(&Wt[(k4 * 4 + kk) * FD]);
            float h = hk[kk];
#pragma unroll
            for (int j4 = 0; j4 < 16; j4++) {
                float4 w = wr[j4];
                acc[4 * j4 + 0] += h * w.x;
                acc[4 * j4 + 1] += h * w.y;
                acc[4 * j4 + 2] += h * w.z;
                acc[4 * j4 + 3] += h * w.w;
            }
        }
    }
    float4* op = (float4*)(tout + (size_t)n * FD);
#pragma unroll
    for (int j4 = 0; j4 < 16; j4++)
        op[j4] = make_float4(acc[4 * j4], acc[4 * j4 + 1], acc[4 * j4 + 2], acc[4 * j4 + 3]);
}

// ---------------- aggregate (pull, CSR), 4 edges/wave-iter + 2x unroll ----------------
// lane = eg(2b) * 16 + fl(4b): eg = edge slot, fl = float4 feature group
__global__ __launch_bounds__(256) void k_agg(const float* __restrict__ t,
                                             const int* __restrict__ row_start,
                                             const int2* __restrict__ edge_cn,
                                             float* __restrict__ out) {
    int node = (blockIdx.x * 256 + threadIdx.x) >> 6;
    int lane = threadIdx.x & 63;
    if (node >= BN) return;
    int p0 = row_start[node];
    int pe = row_start[node + 1];
    int eg = lane >> 4;
    int fl = lane & 15;
    float4 acc = make_float4(0.f, 0.f, 0.f, 0.f);
    for (int p = p0 + eg; p < pe; p += 8) {
        int2 cn0 = edge_cn[p];
        int p1 = p + 4;
        bool has1 = p1 < pe;
        int2 cn1 = has1 ? edge_cn[p1] : make_int2(cn0.x, 0);
        float4 tv0 = ((const float4*)(t + (size_t)cn0.x * FD))[fl];
        float4 tv1 = ((const float4*)(t + (size_t)cn1.x * FD))[fl];
        float n0 = __int_as_float(cn0.y);
        float n1 = __int_as_float(cn1.y);
        acc.x += n0 * tv0.x + n1 * tv1.x;
        acc.y += n0 * tv0.y + n1 * tv1.y;
        acc.z += n0 * tv0.z + n1 * tv1.z;
        acc.w += n0 * tv0.w + n1 * tv1.w;
    }
    // reduce the 4 edge slots: lanes l, l+16, l+32, l+48
    acc.x += __shfl_down(acc.x, 32); acc.y += __shfl_down(acc.y, 32);
    acc.z += __shfl_down(acc.z, 32); acc.w += __shfl_down(acc.w, 32);
    acc.x += __shfl_down(acc.x, 16); acc.y += __shfl_down(acc.y, 16);
    acc.z += __shfl_down(acc.z, 16); acc.w += __shfl_down(acc.w, 16);
    if (lane < 16) {
        float4* op = (float4*)(out + (size_t)node * FD);
        op[fl] = acc;
    }
}

extern "C" void kernel_launch(void* const* d_in, const int* in_sizes, int n_in,
                              void* d_out, int out_size, void* d_ws, size_t ws_size,
                              hipStream_t stream) {
    const float* x  = (const float*)d_in[0];
    const int*   ei = (const int*)d_in[1];
    const float* W1 = (const float*)d_in[2];
    const float* b1 = (const float*)d_in[3];
    const float* W2 = (const float*)d_in[4];
    const float* b2 = (const float*)d_in[5];
    const float* W3 = (const float*)d_in[6];
    const float* b3 = (const float*)d_in[7];
    float* out = (float*)d_out;

    char* ws = (char*)d_ws;
    size_t off = 0;
    float* t        = (float*)(ws + off); off += (size_t)BN * FD * 4;     // 20.48 MB
    int2*  edge_cn  = (int2*)(ws + off);  off += (size_t)TOTE * 8;        // 10.24 MB
    int*   deg      = (int*)(ws + off);   off += (size_t)BN * 4;
    int*   row_start= (int*)(ws + off);   off += (size_t)(BN + 1) * 4;
    float* dinv     = (float*)(ws + off); off += (size_t)BN * 4;
    int*   blocksum = (int*)(ws + off);   off += (size_t)NBLK * 4;
    int*   blockoff = (int*)(ws + off);   off += (size_t)NBLK * 4;
    // rank aliases t's space: rank is dead before the first k_linear writes t
    int*   rank     = (int*)t;

    hipMemsetAsync(deg, 0, (size_t)BN * 4, stream);

    const int eb = (TOTE + 255) / 256;      // 5000
    const int ab = (BN * 64 + 255) / 256;   // 20000

    k_count<<<eb, 256, 0, stream>>>(ei, deg, rank);
    k_dinv_reduce<<<NBLK, 256, 0, stream>>>(deg, dinv, blocksum);
    k_scanblk<<<1, 64, 0, stream>>>(blocksum, blockoff, row_start);
    k_scan2<<<NBLK, 256, 0, stream>>>(deg, blockoff, row_start);
    k_fill<<<eb, 256, 0, stream>>>(ei, row_start, rank, dinv, edge_cn);

    // layer 1: t = x@W1^T + b1 ; h1 = agg(t) -> out
    k_linear<0><<<NBLK, 256, 0, stream>>>(x, W1, b1, t);
    k_agg<<<ab, 256, 0, stream>>>(t, row_start, edge_cn, out);
    // layer 2: t = relu(h1)@W2^T + b2 ; h2 = agg(t) -> out
    k_linear<1><<<NBLK, 256, 0, stream>>>(out, W2, b2, t);
    k_agg<<<ab, 256, 0, stream>>>(t, row_start, edge_cn, out);
    // layer 3: t = relu(h2)@W3^T + b3 ; out = agg(t)
    k_linear<1><<<NBLK, 256, 0, stream>>>(out, W3, b3, t);
    k_agg<<<ab, 256, 0, stream>>>(t, row_start, edge_cn, out);
}